// Round 2
// baseline (4405.654 us; speedup 1.0000x reference)
//
#include <hip/hip_runtime.h>
#include <math.h>

// Problem constants
constexpr int BB = 2, TT = 2048, CC = 1024, HH = 16, HD = 64, EE = 8, FF = 4096;
constexpr int BT = BB * TT;     // 4096 tokens
constexpr int FFC = 1024;       // FF chunk size (4 chunks)

// Workspace layout (units of 4 bytes). Peak = 3*W + ~33K words ~= 50.5 MB.
//  Phase 1: Q=[0,W) K=[W,2W) V=[2W,3W); attn output written IN-PLACE into Q.
//  Phase 2: proj=[2W,3W) (V dead), then hbuf=[0,2W) (Q,K dead), moe=[2W,3W).
//  Smalls at [3W, ...).
constexpr size_t W = (size_t)BT * CC;              // 4,194,304 words
constexpr size_t OFF_Q    = 0;
constexpr size_t OFF_K    = W;
constexpr size_t OFF_V    = 2 * W;
constexpr size_t SM_BASE  = 3 * W;
constexpr size_t SM_GATES = SM_BASE;               // float[8192]
constexpr size_t SM_EIDS  = SM_BASE + 8192;        // int[8192]
constexpr size_t SM_STOK  = SM_BASE + 16384;       // int[8192]
constexpr size_t SM_SGATE = SM_BASE + 24576;       // float[8192]
constexpr size_t SM_CNT   = SM_BASE + 32768;       // int[8]
constexpr size_t SM_OFFS  = SM_BASE + 32776;       // int[8]
constexpr size_t SM_CUR   = SM_BASE + 32784;       // int[8]

__device__ __forceinline__ float gelu_exact(float v) {
    return 0.5f * v * (1.0f + erff(v * 0.70710678118654752440f));
}

// ---------------- shared SGEMM core: 64x64 tile, 4x4 micro, BK=16, 256 thr ----
__device__ __forceinline__ void gemm_core(const float* __restrict__ aload,   // &A[my_load_row][0]
                                          const float* __restrict__ bbase,   // &B[0][n_tile_base]
                                          int ldb, int Kd, float acc[4][4],
                                          float (*As)[64], float (*Bs)[64]) {
    const int t    = threadIdx.x;
    const int kseg = t & 3;          // A load: 4 k-segments of 4
    const int bk   = t >> 4;         // B load row within k-tile
    const int bn   = (t & 15) << 2;  // B load col seg
    const int r    = t >> 2;         // A load row
    const int tc4  = (t & 15) << 2;
    const int tr4  = (t >> 4) << 2;
    for (int k0 = 0; k0 < Kd; k0 += 16) {
        __syncthreads();
        const float4 a = *(const float4*)(aload + k0 + (kseg << 2));
        const float4 b = *(const float4*)(bbase + (size_t)(k0 + bk) * ldb + bn);
        As[(kseg << 2) + 0][r] = a.x;
        As[(kseg << 2) + 1][r] = a.y;
        As[(kseg << 2) + 2][r] = a.z;
        As[(kseg << 2) + 3][r] = a.w;
        *(float4*)&Bs[bk][bn] = b;
        __syncthreads();
#pragma unroll
        for (int kk = 0; kk < 16; ++kk) {
            const float4 av = *(const float4*)&As[kk][tr4];
            const float4 bv = *(const float4*)&Bs[kk][tc4];
            const float aa[4] = {av.x, av.y, av.z, av.w};
            const float bbv[4] = {bv.x, bv.y, bv.z, bv.w};
#pragma unroll
            for (int i = 0; i < 4; ++i)
#pragma unroll
                for (int j = 0; j < 4; ++j)
                    acc[i][j] = fmaf(aa[i], bbv[j], acc[i][j]);
        }
    }
}

// ---------------- QKV projection: q/k/v[bt][h*64+d] = x @ W{q,k,v}[h] ----------
__global__ __launch_bounds__(256) void qkv_kernel(const float* __restrict__ x,
                                                  const float* __restrict__ Wq,
                                                  const float* __restrict__ Wk,
                                                  const float* __restrict__ Wv,
                                                  float* __restrict__ q,
                                                  float* __restrict__ k,
                                                  float* __restrict__ v) {
    __shared__ float As[16][64], Bs[16][64];
    const int mt = blockIdx.x, h = blockIdx.y, wz = blockIdx.z;
    const float* Wm = (wz == 0) ? Wq : ((wz == 1) ? Wk : Wv);
    float* out = (wz == 0) ? q : ((wz == 1) ? k : v);
    const int t = threadIdx.x;
    const float* aload = x + (size_t)(mt * 64 + (t >> 2)) * CC;
    const float* bbase = Wm + (size_t)h * CC * HD;   // [C][64] row-major
    float acc[4][4] = {};
    gemm_core(aload, bbase, HD, CC, acc, As, Bs);
    const int tr4 = (t >> 4) << 2, tc4 = (t & 15) << 2;
#pragma unroll
    for (int i = 0; i < 4; ++i) {
        float4 o4;
        o4.x = acc[i][0]; o4.y = acc[i][1]; o4.z = acc[i][2]; o4.w = acc[i][3];
        *(float4*)&out[(size_t)(mt * 64 + tr4 + i) * CC + h * HD + tc4] = o4;
    }
}

// ---------------- flash-style causal attention, 64-query tile per block -------
// Writes output IN-PLACE into q: each block reads only its own q tile (into LDS,
// up front) and writes the same rows/cols at the end — no cross-block hazard.
__global__ __launch_bounds__(256) void attn_kernel(float* __restrict__ q,
                                                   const float* __restrict__ kbuf,
                                                   const float* __restrict__ vbuf) {
    __shared__ float Qs[64][64];  // [d][r] transposed
    __shared__ float Ks[64][64];  // [d][s] transposed; reused as Ps[s][r]
    __shared__ float Vs[64][64];  // [s][d]
    float (*Ps)[64] = Ks;
    const int qt = blockIdx.x, h = blockIdx.y, b = blockIdx.z;
    const int t = threadIdx.x;
    const int tc4 = (t & 15) << 2, tr4 = (t >> 4) << 2;
    const size_t base = ((size_t)b * TT) * CC + h * HD;
    // load Q tile transposed
#pragma unroll
    for (int it = 0; it < 4; ++it) {
        int fi = t + it * 256;
        int r = fi >> 4, ds = (fi & 15) << 2;
        float4 a = *(const float4*)&q[base + (size_t)(qt * 64 + r) * CC + ds];
        Qs[ds + 0][r] = a.x; Qs[ds + 1][r] = a.y; Qs[ds + 2][r] = a.z; Qs[ds + 3][r] = a.w;
    }
    float o[4][4] = {};
    float m_r[4], l_r[4];
#pragma unroll
    for (int i = 0; i < 4; ++i) { m_r[i] = -INFINITY; l_r[i] = 0.0f; }

    for (int kt = 0; kt <= qt; ++kt) {
        __syncthreads();  // prior-iter Ps/Vs reads done (also covers Q load 1st iter)
#pragma unroll
        for (int it = 0; it < 4; ++it) {
            int fi = t + it * 256;
            int s = fi >> 4, ds = (fi & 15) << 2;
            float4 a = *(const float4*)&kbuf[base + (size_t)(kt * 64 + s) * CC + ds];
            Ks[ds + 0][s] = a.x; Ks[ds + 1][s] = a.y; Ks[ds + 2][s] = a.z; Ks[ds + 3][s] = a.w;
            float4 vv = *(const float4*)&vbuf[base + (size_t)(kt * 64 + s) * CC + ds];
            *(float4*)&Vs[s][ds] = vv;
        }
        __syncthreads();
        // S = Q K^T (64x64), thread holds 4x4
        float s4[4][4] = {};
        for (int d = 0; d < 64; ++d) {
            const float4 av = *(const float4*)&Qs[d][tr4];
            const float4 bv = *(const float4*)&Ks[d][tc4];
            const float aa[4] = {av.x, av.y, av.z, av.w};
            const float bbv[4] = {bv.x, bv.y, bv.z, bv.w};
#pragma unroll
            for (int i = 0; i < 4; ++i)
#pragma unroll
                for (int j = 0; j < 4; ++j)
                    s4[i][j] = fmaf(aa[i], bbv[j], s4[i][j]);
        }
        const float scale = 0.03125f;  // C^-0.5 = 1/32 (faithful: full C, not HD)
#pragma unroll
        for (int i = 0; i < 4; ++i)
#pragma unroll
            for (int j = 0; j < 4; ++j) {
                float sv = s4[i][j] * scale;
                if (kt == qt && (tc4 + j) > (tr4 + i)) sv = -INFINITY;
                s4[i][j] = sv;
            }
        // online softmax update; row group = 16 consecutive lanes within wave
        float p4[4][4];
#pragma unroll
        for (int i = 0; i < 4; ++i) {
            float mt_i = fmaxf(fmaxf(s4[i][0], s4[i][1]), fmaxf(s4[i][2], s4[i][3]));
#pragma unroll
            for (int msk = 1; msk <= 8; msk <<= 1) mt_i = fmaxf(mt_i, __shfl_xor(mt_i, msk, 64));
            float m_new = fmaxf(m_r[i], mt_i);
            float alpha = expf(m_r[i] - m_new);  // exp(-inf)=0 on first tile
            float ls = 0.0f;
#pragma unroll
            for (int j = 0; j < 4; ++j) {
                float p = expf(s4[i][j] - m_new);
                p4[i][j] = p;
                ls += p;
            }
#pragma unroll
            for (int msk = 1; msk <= 8; msk <<= 1) ls += __shfl_xor(ls, msk, 64);
            l_r[i] = l_r[i] * alpha + ls;
            m_r[i] = m_new;
#pragma unroll
            for (int j = 0; j < 4; ++j) o[i][j] *= alpha;
        }
        __syncthreads();  // Ks (S-compute) reads done before overwriting with P
#pragma unroll
        for (int i = 0; i < 4; ++i)
#pragma unroll
            for (int j = 0; j < 4; ++j) Ps[tc4 + j][tr4 + i] = p4[i][j];
        __syncthreads();
        // O += P V
        for (int s = 0; s < 64; ++s) {
            const float4 vv = *(const float4*)&Vs[s][tc4];
            const float vb[4] = {vv.x, vv.y, vv.z, vv.w};
#pragma unroll
            for (int i = 0; i < 4; ++i) {
                const float p = Ps[s][tr4 + i];
#pragma unroll
                for (int j = 0; j < 4; ++j) o[i][j] = fmaf(p, vb[j], o[i][j]);
            }
        }
    }
#pragma unroll
    for (int i = 0; i < 4; ++i) {
        const float inv = 1.0f / l_r[i];
        float4 o4;
        o4.x = o[i][0] * inv; o4.y = o[i][1] * inv; o4.z = o[i][2] * inv; o4.w = o[i][3] * inv;
        *(float4*)&q[base + (size_t)(qt * 64 + tr4 + i) * CC + tc4] = o4;
    }
}

// ---------------- plain GEMM + bias (out-projection) --------------------------
__global__ __launch_bounds__(256) void gemm_bias_kernel(const float* __restrict__ A,
                                                        const float* __restrict__ Bm,
                                                        const float* __restrict__ bias,
                                                        float* __restrict__ out,
                                                        int N, int Kd) {
    __shared__ float As[16][64], Bs[16][64];
    const int mt = blockIdx.x, nt = blockIdx.y;
    const int t = threadIdx.x;
    const float* aload = A + (size_t)(mt * 64 + (t >> 2)) * Kd;
    const float* bbase = Bm + nt * 64;
    float acc[4][4] = {};
    gemm_core(aload, bbase, N, Kd, acc, As, Bs);
    const int tr4 = (t >> 4) << 2, tc4 = (t & 15) << 2;
    const float4 b4 = *(const float4*)&bias[nt * 64 + tc4];
#pragma unroll
    for (int i = 0; i < 4; ++i) {
        float4 o4;
        o4.x = acc[i][0] + b4.x; o4.y = acc[i][1] + b4.y;
        o4.z = acc[i][2] + b4.z; o4.w = acc[i][3] + b4.w;
        *(float4*)&out[(size_t)(mt * 64 + tr4 + i) * N + nt * 64 + tc4] = o4;
    }
}

// ---------------- LayerNorm + residual: out = res + ln(src)*g + b -------------
__device__ __forceinline__ float block_sum(float v, float* red) {
#pragma unroll
    for (int m = 32; m >= 1; m >>= 1) v += __shfl_xor(v, m, 64);
    const int w = threadIdx.x >> 6;
    __syncthreads();
    if ((threadIdx.x & 63) == 0) red[w] = v;
    __syncthreads();
    return red[0] + red[1] + red[2] + red[3];
}

__global__ __launch_bounds__(256) void ln_res_kernel(const float* __restrict__ src,
                                                     const float* __restrict__ res,
                                                     const float* __restrict__ gam,
                                                     const float* __restrict__ bet,
                                                     float* __restrict__ out) {
    __shared__ float red[4];
    const int row = blockIdx.x, t = threadIdx.x;
    const float4 sv = *(const float4*)&src[(size_t)row * CC + t * 4];
    const float total = block_sum(sv.x + sv.y + sv.z + sv.w, red);
    const float mean = total * (1.0f / CC);
    const float d0 = sv.x - mean, d1 = sv.y - mean, d2 = sv.z - mean, d3 = sv.w - mean;
    const float var = block_sum(d0 * d0 + d1 * d1 + d2 * d2 + d3 * d3, red) * (1.0f / CC);
    const float rstd = rsqrtf(var + 1e-5f);
    const float4 rv = *(const float4*)&res[(size_t)row * CC + t * 4];
    const float4 g4 = *(const float4*)&gam[t * 4];
    const float4 b4 = *(const float4*)&bet[t * 4];
    float4 o4;
    o4.x = rv.x + d0 * rstd * g4.x + b4.x;
    o4.y = rv.y + d1 * rstd * g4.y + b4.y;
    o4.z = rv.z + d2 * rstd * g4.z + b4.z;
    o4.w = rv.w + d3 * rstd * g4.w + b4.w;
    *(float4*)&out[(size_t)row * CC + t * 4] = o4;
}

// ---------------- router: noisy top-2 gates + per-expert counts ---------------
__global__ __launch_bounds__(256) void router_kernel(const float* __restrict__ x1,
                                                     const float* __restrict__ Wr,
                                                     const float* __restrict__ br,
                                                     const float* __restrict__ Wn,
                                                     const float* __restrict__ bn,
                                                     const float* __restrict__ noise,
                                                     float* __restrict__ gates,
                                                     int* __restrict__ eids,
                                                     int* __restrict__ counts) {
    __shared__ float xs[CC];
    __shared__ float part[256];
    __shared__ float dots[16];
    const int tk = blockIdx.x, t = threadIdx.x;
    *(float4*)&xs[t * 4] = *(const float4*)&x1[(size_t)tk * CC + t * 4];
    __syncthreads();
    const int o = t & 15, cs = t >> 4;
    float acc = 0.0f;
    if (o < 8) {
        for (int c = cs; c < CC; c += 16) acc += xs[c] * Wr[c * EE + o];
    } else {
        const int e = o - 8;
        for (int c = cs; c < CC; c += 16) acc += xs[c] * Wn[c * EE + e];
    }
    part[t] = acc;
    __syncthreads();
    if (t < 16) {
        float s = 0.0f;
        for (int i = 0; i < 16; ++i) s += part[t + 16 * i];
        dots[t] = s;
    }
    __syncthreads();
    if (t == 0) {
        float noisy[EE];
        for (int e = 0; e < EE; ++e) {
            const float lg = dots[e] + br[e];
            const float nl = dots[8 + e] + bn[e];
            const float sp = fmaxf(nl, 0.0f) + log1pf(expf(-fabsf(nl)));  // stable softplus
            noisy[e] = lg + noise[(size_t)tk * EE + e] * sp;
        }
        int e1 = 0; float v1 = noisy[0];
        for (int e = 1; e < EE; ++e) if (noisy[e] > v1) { v1 = noisy[e]; e1 = e; }
        int e2 = -1; float v2 = -INFINITY;
        for (int e = 0; e < EE; ++e) if (e != e1 && noisy[e] > v2) { v2 = noisy[e]; e2 = e; }
        const float ex = expf(v2 - v1);
        const float inv = 1.0f / (1.0f + ex);
        gates[2 * tk] = inv; gates[2 * tk + 1] = ex * inv;
        eids[2 * tk] = e1; eids[2 * tk + 1] = e2;
        atomicAdd(&counts[e1], 1);
        atomicAdd(&counts[e2], 1);
    }
}

__global__ void zero_counts_kernel(int* __restrict__ cnt) {
    if (threadIdx.x < EE) cnt[threadIdx.x] = 0;
}

__global__ void offsets_kernel(const int* __restrict__ cnt, int* __restrict__ offs,
                               int* __restrict__ cur) {
    const int t = threadIdx.x;
    if (t == 0) {
        int a = 0;
        for (int e = 0; e < EE; ++e) { offs[e] = a; a += cnt[e]; }
    }
    if (t < EE) cur[t] = 0;
}

__global__ __launch_bounds__(256) void scatter_kernel(const int* __restrict__ eids,
                                                      const float* __restrict__ gates,
                                                      int* __restrict__ cur,
                                                      const int* __restrict__ offs,
                                                      int* __restrict__ slot_token,
                                                      float* __restrict__ slot_gate) {
    const int tk = blockIdx.x * 256 + threadIdx.x;
    if (tk >= BT) return;
#pragma unroll
    for (int ki = 0; ki < 2; ++ki) {
        const int e = eids[2 * tk + ki];
        const int idx = atomicAdd(&cur[e], 1);
        const int slot = offs[e] + idx;
        slot_token[slot] = tk;
        slot_gate[slot] = gates[2 * tk + ki];
    }
}

// ---------------- zero a float buffer (moe accumulator init) ------------------
__global__ __launch_bounds__(256) void zero_kernel(float* __restrict__ p, int n4) {
    const int i = blockIdx.x * 256 + threadIdx.x;
    if (i < n4) ((float4*)p)[i] = make_float4(0.f, 0.f, 0.f, 0.f);
}

// ---------------- expert FFN layer 1 (gathered rows, +b1, exact GELU) ---------
__global__ __launch_bounds__(256) void moe_gemm1(const float* __restrict__ x1,
                                                 const float* __restrict__ W1,
                                                 const float* __restrict__ b1,
                                                 const int* __restrict__ slot_token,
                                                 const int* __restrict__ offs,
                                                 const int* __restrict__ cnt,
                                                 float* __restrict__ hbuf, int fbase) {
    __shared__ float As[16][64], Bs[16][64];
    const int e = blockIdx.z;
    const int ne = cnt[e];
    const int mt = blockIdx.x;
    if (mt * 64 >= ne) return;
    const int t = threadIdx.x;
    int rl = mt * 64 + (t >> 2);
    if (rl >= ne) rl = ne - 1;  // clamp (stores guarded below)
    const int token = slot_token[offs[e] + rl];
    const float* aload = x1 + (size_t)token * CC;
    const int nb = blockIdx.y * 64;  // col within chunk
    const float* bbase = W1 + (size_t)e * CC * FF + fbase + nb;
    float acc[4][4] = {};
    gemm_core(aload, bbase, FF, CC, acc, As, Bs);
    const int tr4 = (t >> 4) << 2, tc4 = (t & 15) << 2;
    const float4 bb4 = *(const float4*)&b1[(size_t)e * FF + fbase + nb + tc4];
#pragma unroll
    for (int i = 0; i < 4; ++i) {
        const int rloc = mt * 64 + tr4 + i;
        if (rloc < ne) {
            const size_t slot = (size_t)offs[e] + rloc;
            float4 o4;
            o4.x = gelu_exact(acc[i][0] + bb4.x);
            o4.y = gelu_exact(acc[i][1] + bb4.y);
            o4.z = gelu_exact(acc[i][2] + bb4.z);
            o4.w = gelu_exact(acc[i][3] + bb4.w);
            *(float4*)&hbuf[slot * FFC + nb + tc4] = o4;
        }
    }
}

// ---------------- expert FFN layer 2: gate-weighted atomic accumulate ---------
__global__ __launch_bounds__(256) void moe_gemm2(const float* __restrict__ hbuf,
                                                 const float* __restrict__ W2,
                                                 const float* __restrict__ b2,
                                                 const int* __restrict__ offs,
                                                 const int* __restrict__ cnt,
                                                 const int* __restrict__ slot_token,
                                                 const float* __restrict__ slot_gate,
                                                 float* __restrict__ moe,
                                                 int fbase, int first) {
    __shared__ float As[16][64], Bs[16][64];
    const int e = blockIdx.z;
    const int ne = cnt[e];
    const int mt = blockIdx.x;
    if (mt * 64 >= ne) return;
    const int t = threadIdx.x;
    int rl = mt * 64 + (t >> 2);
    if (rl >= ne) rl = ne - 1;
    const float* aload = hbuf + (size_t)(offs[e] + rl) * FFC;
    const int nb = blockIdx.y * 64;
    const float* bbase = W2 + (size_t)e * FF * CC + (size_t)fbase * CC + nb;
    float acc[4][4] = {};
    gemm_core(aload, bbase, CC, FFC, acc, As, Bs);
    const int tr4 = (t >> 4) << 2, tc4 = (t & 15) << 2;
    float4 bias4 = make_float4(0.f, 0.f, 0.f, 0.f);
    if (first) bias4 = *(const float4*)&b2[(size_t)e * CC + nb + tc4];
#pragma unroll
    for (int i = 0; i < 4; ++i) {
        const int rloc = mt * 64 + tr4 + i;
        if (rloc < ne) {
            const int slot = offs[e] + rloc;
            const int token = slot_token[slot];
            const float g = slot_gate[slot];
            float* dst = &moe[(size_t)token * CC + nb + tc4];
            atomicAdd(dst + 0, g * (acc[i][0] + bias4.x));
            atomicAdd(dst + 1, g * (acc[i][1] + bias4.y));
            atomicAdd(dst + 2, g * (acc[i][2] + bias4.z));
            atomicAdd(dst + 3, g * (acc[i][3] + bias4.w));
        }
    }
}

// ---------------- launch ------------------------------------------------------
extern "C" void kernel_launch(void* const* d_in, const int* in_sizes, int n_in,
                              void* d_out, int out_size, void* d_ws, size_t ws_size,
                              hipStream_t stream) {
    (void)in_sizes; (void)n_in; (void)out_size; (void)ws_size;
    const float* x    = (const float*)d_in[0];
    const float* Wq   = (const float*)d_in[1];
    const float* Wk   = (const float*)d_in[2];
    const float* Wv   = (const float*)d_in[3];
    const float* Wo   = (const float*)d_in[4];
    const float* bo   = (const float*)d_in[5];
    const float* ln1g = (const float*)d_in[6];
    const float* ln1b = (const float*)d_in[7];
    const float* Wr   = (const float*)d_in[8];
    const float* br   = (const float*)d_in[9];
    const float* Wn   = (const float*)d_in[10];
    const float* bn   = (const float*)d_in[11];
    const float* W1   = (const float*)d_in[12];
    const float* b1   = (const float*)d_in[13];
    const float* W2   = (const float*)d_in[14];
    const float* b2   = (const float*)d_in[15];
    const float* ln2g = (const float*)d_in[16];
    const float* ln2b = (const float*)d_in[17];
    const float* noise= (const float*)d_in[18];
    float* out = (float*)d_out;
    float* ws  = (float*)d_ws;
    int*   iws = (int*)d_ws;

    float* qb    = ws + OFF_Q;     // Q, then attn output (in-place)
    float* kb    = ws + OFF_K;
    float* vb    = ws + OFF_V;
    float* proj  = ws + OFF_V;     // V dead after attention
    float* x1    = out;            // x1 lives in d_out (final ln2 in-place safe)
    float* hbuf  = ws + OFF_Q;     // spans Q+K regions (8192 x FFC), dead by then
    float* moe   = ws + OFF_V;     // proj dead after ln1
    float* gates = ws + SM_GATES;
    float* sgate = ws + SM_SGATE;
    int* eids  = iws + SM_EIDS;
    int* stok  = iws + SM_STOK;
    int* cnt   = iws + SM_CNT;
    int* offs  = iws + SM_OFFS;
    int* cur   = iws + SM_CUR;

    zero_counts_kernel<<<1, 64, 0, stream>>>(cnt);
    qkv_kernel<<<dim3(BT / 64, HH, 3), 256, 0, stream>>>(x, Wq, Wk, Wv, qb, kb, vb);
    attn_kernel<<<dim3(TT / 64, HH, BB), 256, 0, stream>>>(qb, kb, vb);
    gemm_bias_kernel<<<dim3(BT / 64, CC / 64), 256, 0, stream>>>(qb, Wo, bo, proj, CC, CC);
    ln_res_kernel<<<BT, 256, 0, stream>>>(proj, x, ln1g, ln1b, x1);
    router_kernel<<<BT, 256, 0, stream>>>(x1, Wr, br, Wn, bn, noise, gates, eids, cnt);
    offsets_kernel<<<1, 64, 0, stream>>>(cnt, offs, cur);
    scatter_kernel<<<BT / 256, 256, 0, stream>>>(eids, gates, cur, offs, stok, sgate);
    zero_kernel<<<(BT * CC / 4 + 255) / 256, 256, 0, stream>>>(moe, BT * CC / 4);
    for (int ccnk = 0; ccnk < FF / FFC; ++ccnk) {
        moe_gemm1<<<dim3(64, FFC / 64, EE), 256, 0, stream>>>(x1, W1, b1, stok, offs, cnt,
                                                              hbuf, ccnk * FFC);
        moe_gemm2<<<dim3(64, CC / 64, EE), 256, 0, stream>>>(hbuf, W2, b2, offs, cnt,
                                                             stok, sgate, moe,
                                                             ccnk * FFC, ccnk == 0 ? 1 : 0);
    }
    ln_res_kernel<<<BT, 256, 0, stream>>>(moe, x1, ln2g, ln2b, out);
}

// Round 4
// 2697.255 us; speedup vs baseline: 1.6334x; 1.6334x over previous
//
#include <hip/hip_runtime.h>
#include <math.h>

// Problem constants
constexpr int BB = 2, TT = 2048, CC = 1024, HH = 16, HD = 64, EE = 8, FF = 4096;
constexpr int BT = BB * TT;     // 4096 tokens
constexpr int FFC = 1024;       // FF chunk size (4 chunks)

// Workspace layout (units of 4 bytes). Peak ~= 50.5 MB (same as passing round 2).
constexpr size_t W = (size_t)BT * CC;              // 4,194,304 words
constexpr size_t OFF_Q    = 0;
constexpr size_t OFF_K    = W;
constexpr size_t OFF_V    = 2 * W;
constexpr size_t SM_BASE  = 3 * W;
constexpr size_t SM_GATES = SM_BASE;               // float[8192]
constexpr size_t SM_EIDS  = SM_BASE + 8192;        // int[8192]
constexpr size_t SM_STOK  = SM_BASE + 16384;       // int[8192]
constexpr size_t SM_SGATE = SM_BASE + 24576;       // float[8192]
constexpr size_t SM_CNT   = SM_BASE + 32768;       // int[8]
constexpr size_t SM_OFFS  = SM_BASE + 32776;       // int[8]
constexpr size_t SM_CUR   = SM_BASE + 32784;       // int[8]

typedef short bf16x8 __attribute__((ext_vector_type(8)));
typedef float f32x4  __attribute__((ext_vector_type(4)));

__device__ __forceinline__ float gelu_exact(float v) {
    return 0.5f * v * (1.0f + erff(v * 0.70710678118654752440f));
}

__device__ __forceinline__ short f2bf(float f) {   // RNE fp32->bf16
    unsigned u = __float_as_uint(f);
    unsigned r = 0x7fffu + ((u >> 16) & 1u);
    return (short)((u + r) >> 16);
}

__device__ __forceinline__ bf16x8 pack8(float4 a, float4 b) {
    bf16x8 o;
    o[0] = f2bf(a.x); o[1] = f2bf(a.y); o[2] = f2bf(a.z); o[3] = f2bf(a.w);
    o[4] = f2bf(b.x); o[5] = f2bf(b.y); o[6] = f2bf(b.z); o[7] = f2bf(b.w);
    return o;
}

// =================== fp32 SGEMM core (pre-router chain; EXACT r2) =============
__device__ __forceinline__ void gemm_core(const float* __restrict__ aload,
                                          const float* __restrict__ bbase,
                                          int ldb, int Kd, float acc[4][4],
                                          float (*As)[64], float (*Bs)[64]) {
    const int t    = threadIdx.x;
    const int kseg = t & 3;
    const int bk   = t >> 4;
    const int bnn  = (t & 15) << 2;
    const int r    = t >> 2;
    const int tc4  = (t & 15) << 2;
    const int tr4  = (t >> 4) << 2;
    for (int k0 = 0; k0 < Kd; k0 += 16) {
        __syncthreads();
        const float4 a = *(const float4*)(aload + k0 + (kseg << 2));
        const float4 b = *(const float4*)(bbase + (size_t)(k0 + bk) * ldb + bnn);
        As[(kseg << 2) + 0][r] = a.x;
        As[(kseg << 2) + 1][r] = a.y;
        As[(kseg << 2) + 2][r] = a.z;
        As[(kseg << 2) + 3][r] = a.w;
        *(float4*)&Bs[bk][bnn] = b;
        __syncthreads();
#pragma unroll
        for (int kk = 0; kk < 16; ++kk) {
            const float4 av = *(const float4*)&As[kk][tr4];
            const float4 bv = *(const float4*)&Bs[kk][tc4];
            const float aa[4] = {av.x, av.y, av.z, av.w};
            const float bbv[4] = {bv.x, bv.y, bv.z, bv.w};
#pragma unroll
            for (int i = 0; i < 4; ++i)
#pragma unroll
                for (int j = 0; j < 4; ++j)
                    acc[i][j] = fmaf(aa[i], bbv[j], acc[i][j]);
        }
    }
}

// ---------------- QKV projection (fp32, exact round-2) ------------------------
__global__ __launch_bounds__(256) void qkv_kernel(const float* __restrict__ x,
                                                  const float* __restrict__ Wq,
                                                  const float* __restrict__ Wk,
                                                  const float* __restrict__ Wv,
                                                  float* __restrict__ q,
                                                  float* __restrict__ k,
                                                  float* __restrict__ v) {
    __shared__ float As[16][64], Bs[16][64];
    const int mt = blockIdx.x, h = blockIdx.y, wz = blockIdx.z;
    const float* Wm = (wz == 0) ? Wq : ((wz == 1) ? Wk : Wv);
    float* out = (wz == 0) ? q : ((wz == 1) ? k : v);
    const int t = threadIdx.x;
    const float* aload = x + (size_t)(mt * 64 + (t >> 2)) * CC;
    const float* bbase = Wm + (size_t)h * CC * HD;
    float acc[4][4] = {};
    gemm_core(aload, bbase, HD, CC, acc, As, Bs);
    const int tr4 = (t >> 4) << 2, tc4 = (t & 15) << 2;
#pragma unroll
    for (int i = 0; i < 4; ++i) {
        float4 o4;
        o4.x = acc[i][0]; o4.y = acc[i][1]; o4.z = acc[i][2]; o4.w = acc[i][3];
        *(float4*)&out[(size_t)(mt * 64 + tr4 + i) * CC + h * HD + tc4] = o4;
    }
}

// ---------------- plain GEMM + bias (fp32 out-projection, exact round-2) ------
__global__ __launch_bounds__(256) void gemm_bias_kernel(const float* __restrict__ A,
                                                        const float* __restrict__ Bm,
                                                        const float* __restrict__ bias,
                                                        float* __restrict__ out,
                                                        int N, int Kd) {
    __shared__ float As[16][64], Bs[16][64];
    const int mt = blockIdx.x, nt = blockIdx.y;
    const int t = threadIdx.x;
    const float* aload = A + (size_t)(mt * 64 + (t >> 2)) * Kd;
    const float* bbase = Bm + nt * 64;
    float acc[4][4] = {};
    gemm_core(aload, bbase, N, Kd, acc, As, Bs);
    const int tr4 = (t >> 4) << 2, tc4 = (t & 15) << 2;
    const float4 b4 = *(const float4*)&bias[nt * 64 + tc4];
#pragma unroll
    for (int i = 0; i < 4; ++i) {
        float4 o4;
        o4.x = acc[i][0] + b4.x; o4.y = acc[i][1] + b4.y;
        o4.z = acc[i][2] + b4.z; o4.w = acc[i][3] + b4.w;
        *(float4*)&out[(size_t)(mt * 64 + tr4 + i) * N + nt * 64 + tc4] = o4;
    }
}

// ---------------- flash-style causal attention, paired q-tiles (fp32) ---------
// Per-tile math identical to round 2 (zero numeric delta); block handles
// qt=blockIdx.x and qt=31-blockIdx.x for load balance. In-place output into q.
__global__ __launch_bounds__(256) void attn_kernel(float* __restrict__ q,
                                                   const float* __restrict__ kbuf,
                                                   const float* __restrict__ vbuf) {
    __shared__ float Qs[64][64];
    __shared__ float Ks[64][64];
    __shared__ float Vs[64][64];
    float (*Ps)[64] = Ks;
    const int h = blockIdx.y, b = blockIdx.z;
    const int t = threadIdx.x;
    const int tc4 = (t & 15) << 2, tr4 = (t >> 4) << 2;
    const size_t base = ((size_t)b * TT) * CC + h * HD;
#pragma unroll 1
    for (int pass = 0; pass < 2; ++pass) {
        const int qt = pass == 0 ? blockIdx.x : (TT / 64 - 1 - blockIdx.x);
        __syncthreads();
#pragma unroll
        for (int it = 0; it < 4; ++it) {
            int fi = t + it * 256;
            int r = fi >> 4, ds = (fi & 15) << 2;
            float4 a = *(const float4*)&q[base + (size_t)(qt * 64 + r) * CC + ds];
            Qs[ds + 0][r] = a.x; Qs[ds + 1][r] = a.y; Qs[ds + 2][r] = a.z; Qs[ds + 3][r] = a.w;
        }
        float o[4][4] = {};
        float m_r[4], l_r[4];
#pragma unroll
        for (int i = 0; i < 4; ++i) { m_r[i] = -INFINITY; l_r[i] = 0.0f; }

        for (int kt = 0; kt <= qt; ++kt) {
            __syncthreads();
#pragma unroll
            for (int it = 0; it < 4; ++it) {
                int fi = t + it * 256;
                int s = fi >> 4, ds = (fi & 15) << 2;
                float4 a = *(const float4*)&kbuf[base + (size_t)(kt * 64 + s) * CC + ds];
                Ks[ds + 0][s] = a.x; Ks[ds + 1][s] = a.y; Ks[ds + 2][s] = a.z; Ks[ds + 3][s] = a.w;
                float4 vv = *(const float4*)&vbuf[base + (size_t)(kt * 64 + s) * CC + ds];
                *(float4*)&Vs[s][ds] = vv;
            }
            __syncthreads();
            float s4[4][4] = {};
            for (int d = 0; d < 64; ++d) {
                const float4 av = *(const float4*)&Qs[d][tr4];
                const float4 bv = *(const float4*)&Ks[d][tc4];
                const float aa[4] = {av.x, av.y, av.z, av.w};
                const float bbv[4] = {bv.x, bv.y, bv.z, bv.w};
#pragma unroll
                for (int i = 0; i < 4; ++i)
#pragma unroll
                    for (int j = 0; j < 4; ++j)
                        s4[i][j] = fmaf(aa[i], bbv[j], s4[i][j]);
            }
            const float scale = 0.03125f;  // C^-0.5 (faithful: full C)
#pragma unroll
            for (int i = 0; i < 4; ++i)
#pragma unroll
                for (int j = 0; j < 4; ++j) {
                    float sv = s4[i][j] * scale;
                    if (kt == qt && (tc4 + j) > (tr4 + i)) sv = -INFINITY;
                    s4[i][j] = sv;
                }
            float p4[4][4];
#pragma unroll
            for (int i = 0; i < 4; ++i) {
                float mt_i = fmaxf(fmaxf(s4[i][0], s4[i][1]), fmaxf(s4[i][2], s4[i][3]));
#pragma unroll
                for (int msk = 1; msk <= 8; msk <<= 1) mt_i = fmaxf(mt_i, __shfl_xor(mt_i, msk, 64));
                float m_new = fmaxf(m_r[i], mt_i);
                float alpha = expf(m_r[i] - m_new);
                float ls = 0.0f;
#pragma unroll
                for (int j = 0; j < 4; ++j) {
                    float p = expf(s4[i][j] - m_new);
                    p4[i][j] = p;
                    ls += p;
                }
#pragma unroll
                for (int msk = 1; msk <= 8; msk <<= 1) ls += __shfl_xor(ls, msk, 64);
                l_r[i] = l_r[i] * alpha + ls;
                m_r[i] = m_new;
#pragma unroll
                for (int j = 0; j < 4; ++j) o[i][j] *= alpha;
            }
            __syncthreads();
#pragma unroll
            for (int i = 0; i < 4; ++i)
#pragma unroll
                for (int j = 0; j < 4; ++j) Ps[tc4 + j][tr4 + i] = p4[i][j];
            __syncthreads();
            for (int s = 0; s < 64; ++s) {
                const float4 vv = *(const float4*)&Vs[s][tc4];
                const float vb[4] = {vv.x, vv.y, vv.z, vv.w};
#pragma unroll
                for (int i = 0; i < 4; ++i) {
                    const float p = Ps[s][tr4 + i];
#pragma unroll
                    for (int j = 0; j < 4; ++j) o[i][j] = fmaf(p, vb[j], o[i][j]);
                }
            }
        }
#pragma unroll
        for (int i = 0; i < 4; ++i) {
            const float inv = 1.0f / l_r[i];
            float4 o4;
            o4.x = o[i][0] * inv; o4.y = o[i][1] * inv; o4.z = o[i][2] * inv; o4.w = o[i][3] * inv;
            *(float4*)&q[base + (size_t)(qt * 64 + tr4 + i) * CC + tc4] = o4;
        }
    }
}

// ======================= bf16 MFMA blocks (FFN only) ==========================
// Tile 128x128, BK=32, 256 threads = 4 waves 2x2, wave does 4x4 of 16x16x32.
__device__ __forceinline__ void stage_a(const float* __restrict__ p, short* dst) {
    const float4 f0 = *(const float4*)(p + 0);
    const float4 f1 = *(const float4*)(p + 4);
    const float4 f2 = *(const float4*)(p + 8);
    const float4 f3 = *(const float4*)(p + 12);
    *(bf16x8*)dst       = pack8(f0, f1);
    *(bf16x8*)(dst + 8) = pack8(f2, f3);
}

__device__ __forceinline__ void stage_b(const float* __restrict__ base, int stride,
                                        short* dst) {
#pragma unroll
    for (int half = 0; half < 2; ++half) {
        float v[8];
#pragma unroll
        for (int kk = 0; kk < 8; ++kk) v[kk] = base[(size_t)(half * 8 + kk) * stride];
        bf16x8 o;
#pragma unroll
        for (int kk = 0; kk < 8; ++kk) o[kk] = f2bf(v[kk]);
        *(bf16x8*)(dst + half * 8) = o;
    }
}

__device__ __forceinline__ void compute_step(short (*As)[40], short (*Bs)[40],
                                             f32x4 acc[4][4], int wm, int wn,
                                             int l15, int q8) {
    bf16x8 a[4], b[4];
#pragma unroll
    for (int i = 0; i < 4; ++i) a[i] = *(bf16x8*)&As[wm + i * 16 + l15][q8];
#pragma unroll
    for (int j = 0; j < 4; ++j) b[j] = *(bf16x8*)&Bs[wn + j * 16 + l15][q8];
#pragma unroll
    for (int i = 0; i < 4; ++i)
#pragma unroll
        for (int j = 0; j < 4; ++j)
            acc[i][j] = __builtin_amdgcn_mfma_f32_16x16x32_bf16(a[i], b[j], acc[i][j], 0, 0, 0);
}

#define MM_PROLOG                                                    \
    const int t = threadIdx.x, lane = t & 63, wid = t >> 6;          \
    const int wm = (wid >> 1) * 64, wn = (wid & 1) * 64;             \
    const int l15 = lane & 15, q8 = (lane >> 4) * 8;                 \
    const int arow = t >> 1, akh = (t & 1) * 16;                     \
    const int bn = t & 127, bkh = (t >> 7) * 16;

// ---------------- MoE FFN layer 1: gathered rows, +b1, exact GELU -> hbuf ----
__global__ __launch_bounds__(256) void mm_ffn1(const float* __restrict__ x1,
                                               const float* __restrict__ W1,
                                               const float* __restrict__ b1,
                                               const int* __restrict__ stok,
                                               const int* __restrict__ offs,
                                               const int* __restrict__ cnt,
                                               float* __restrict__ hbuf, int fbase) {
    __shared__ short As[128][40], Bs[128][40];
    const int e = blockIdx.z, mt = blockIdx.x, nt = blockIdx.y;
    const int ne = cnt[e];
    if (mt * 128 >= ne) return;
    MM_PROLOG
    const int off_e = offs[e];
    int rl = mt * 128 + arow;
    if (rl >= ne) rl = ne - 1;
    const int token = stok[off_e + rl];
    const float* ap = x1 + (size_t)token * CC;
    const float* bp = W1 + (size_t)e * CC * FF + fbase + nt * 128 + bn;
    f32x4 acc[4][4] = {};
    for (int k0 = 0; k0 < CC; k0 += 32) {
        __syncthreads();
        stage_a(ap + k0 + akh, &As[arow][akh]);
        stage_b(bp + (size_t)(k0 + bkh) * FF, FF, &Bs[bn][bkh]);
        __syncthreads();
        compute_step(As, Bs, acc, wm, wn, l15, q8);
    }
    float bj[4];
#pragma unroll
    for (int j = 0; j < 4; ++j)
        bj[j] = b1[(size_t)e * FF + fbase + nt * 128 + wn + j * 16 + l15];
    const int colb = nt * 128 + wn;   // chunk-local column
#pragma unroll
    for (int i = 0; i < 4; ++i) {
#pragma unroll
        for (int r = 0; r < 4; ++r) {
            const int row = mt * 128 + wm + i * 16 + (lane >> 4) * 4 + r;
            if (row < ne) {
                float* orow = hbuf + (size_t)(off_e + row) * FFC + colb;
#pragma unroll
                for (int j = 0; j < 4; ++j)
                    orow[j * 16 + l15] = gelu_exact(acc[i][j][r] + bj[j]);
            }
        }
    }
}

// ---------------- MoE FFN layer 2: gate-weighted atomic accumulate -----------
__global__ __launch_bounds__(256) void mm_ffn2(const float* __restrict__ hbuf,
                                               const float* __restrict__ W2,
                                               const float* __restrict__ b2,
                                               const int* __restrict__ stok,
                                               const float* __restrict__ sgate,
                                               const int* __restrict__ offs,
                                               const int* __restrict__ cnt,
                                               float* __restrict__ moe,
                                               int fbase, int first) {
    __shared__ short As[128][40], Bs[128][40];
    const int e = blockIdx.z, mt = blockIdx.x, nt = blockIdx.y;
    const int ne = cnt[e];
    if (mt * 128 >= ne) return;
    MM_PROLOG
    const int off_e = offs[e];
    int rl = mt * 128 + arow;
    if (rl >= ne) rl = ne - 1;
    const float* ap = hbuf + (size_t)(off_e + rl) * FFC;
    const float* bp = W2 + (size_t)e * FF * CC + (size_t)fbase * CC + nt * 128 + bn;
    f32x4 acc[4][4] = {};
    for (int k0 = 0; k0 < FFC; k0 += 32) {
        __syncthreads();
        stage_a(ap + k0 + akh, &As[arow][akh]);
        stage_b(bp + (size_t)(k0 + bkh) * CC, CC, &Bs[bn][bkh]);
        __syncthreads();
        compute_step(As, Bs, acc, wm, wn, l15, q8);
    }
    float bj[4];
    int colj[4];
#pragma unroll
    for (int j = 0; j < 4; ++j) {
        colj[j] = nt * 128 + wn + j * 16 + l15;
        bj[j] = first ? b2[(size_t)e * CC + colj[j]] : 0.0f;
    }
#pragma unroll
    for (int i = 0; i < 4; ++i) {
#pragma unroll
        for (int r = 0; r < 4; ++r) {
            const int row = mt * 128 + wm + i * 16 + (lane >> 4) * 4 + r;
            if (row < ne) {
                const int slot = off_e + row;
                const int token = stok[slot];
                const float g = sgate[slot];
                float* dst = moe + (size_t)token * CC;
#pragma unroll
                for (int j = 0; j < 4; ++j)
                    atomicAdd(dst + colj[j], g * (acc[i][j][r] + bj[j]));
            }
        }
    }
}

// ---------------- LayerNorm + residual ----------------------------------------
__device__ __forceinline__ float block_sum(float v, float* red) {
#pragma unroll
    for (int m = 32; m >= 1; m >>= 1) v += __shfl_xor(v, m, 64);
    const int w = threadIdx.x >> 6;
    __syncthreads();
    if ((threadIdx.x & 63) == 0) red[w] = v;
    __syncthreads();
    return red[0] + red[1] + red[2] + red[3];
}

__global__ __launch_bounds__(256) void ln_res_kernel(const float* __restrict__ src,
                                                     const float* __restrict__ res,
                                                     const float* __restrict__ gam,
                                                     const float* __restrict__ bet,
                                                     float* __restrict__ out) {
    __shared__ float red[4];
    const int row = blockIdx.x, t = threadIdx.x;
    const float4 sv = *(const float4*)&src[(size_t)row * CC + t * 4];
    const float total = block_sum(sv.x + sv.y + sv.z + sv.w, red);
    const float mean = total * (1.0f / CC);
    const float d0 = sv.x - mean, d1 = sv.y - mean, d2 = sv.z - mean, d3 = sv.w - mean;
    const float var = block_sum(d0 * d0 + d1 * d1 + d2 * d2 + d3 * d3, red) * (1.0f / CC);
    const float rstd = rsqrtf(var + 1e-5f);
    const float4 rv = *(const float4*)&res[(size_t)row * CC + t * 4];
    const float4 g4 = *(const float4*)&gam[t * 4];
    const float4 b4 = *(const float4*)&bet[t * 4];
    float4 o4;
    o4.x = rv.x + d0 * rstd * g4.x + b4.x;
    o4.y = rv.y + d1 * rstd * g4.y + b4.y;
    o4.z = rv.z + d2 * rstd * g4.z + b4.z;
    o4.w = rv.w + d3 * rstd * g4.w + b4.w;
    *(float4*)&out[(size_t)row * CC + t * 4] = o4;
}

// ---------------- router: noisy top-2 gates + per-expert counts ---------------
__global__ __launch_bounds__(256) void router_kernel(const float* __restrict__ x1,
                                                     const float* __restrict__ Wr,
                                                     const float* __restrict__ br,
                                                     const float* __restrict__ Wn,
                                                     const float* __restrict__ bn,
                                                     const float* __restrict__ noise,
                                                     float* __restrict__ gates,
                                                     int* __restrict__ eids,
                                                     int* __restrict__ counts) {
    __shared__ float xs[CC];
    __shared__ float part[256];
    __shared__ float dots[16];
    const int tk = blockIdx.x, t = threadIdx.x;
    *(float4*)&xs[t * 4] = *(const float4*)&x1[(size_t)tk * CC + t * 4];
    __syncthreads();
    const int o = t & 15, cs = t >> 4;
    float acc = 0.0f;
    if (o < 8) {
        for (int c = cs; c < CC; c += 16) acc += xs[c] * Wr[c * EE + o];
    } else {
        const int e = o - 8;
        for (int c = cs; c < CC; c += 16) acc += xs[c] * Wn[c * EE + e];
    }
    part[t] = acc;
    __syncthreads();
    if (t < 16) {
        float s = 0.0f;
        for (int i = 0; i < 16; ++i) s += part[t + 16 * i];
        dots[t] = s;
    }
    __syncthreads();
    if (t == 0) {
        float noisy[EE];
        for (int e = 0; e < EE; ++e) {
            const float lg = dots[e] + br[e];
            const float nl = dots[8 + e] + bn[e];
            const float sp = fmaxf(nl, 0.0f) + log1pf(expf(-fabsf(nl)));
            noisy[e] = lg + noise[(size_t)tk * EE + e] * sp;
        }
        int e1 = 0; float v1 = noisy[0];
        for (int e = 1; e < EE; ++e) if (noisy[e] > v1) { v1 = noisy[e]; e1 = e; }
        int e2 = -1; float v2 = -INFINITY;
        for (int e = 0; e < EE; ++e) if (e != e1 && noisy[e] > v2) { v2 = noisy[e]; e2 = e; }
        const float ex = expf(v2 - v1);
        const float inv = 1.0f / (1.0f + ex);
        gates[2 * tk] = inv; gates[2 * tk + 1] = ex * inv;
        eids[2 * tk] = e1; eids[2 * tk + 1] = e2;
        atomicAdd(&counts[e1], 1);
        atomicAdd(&counts[e2], 1);
    }
}

__global__ void zero_counts_kernel(int* __restrict__ cnt) {
    if (threadIdx.x < EE) cnt[threadIdx.x] = 0;
}

__global__ void offsets_kernel(const int* __restrict__ cnt, int* __restrict__ offs,
                               int* __restrict__ cur) {
    const int t = threadIdx.x;
    if (t == 0) {
        int a = 0;
        for (int e = 0; e < EE; ++e) { offs[e] = a; a += cnt[e]; }
    }
    if (t < EE) cur[t] = 0;
}

__global__ __launch_bounds__(256) void scatter_kernel(const int* __restrict__ eids,
                                                      const float* __restrict__ gates,
                                                      int* __restrict__ cur,
                                                      const int* __restrict__ offs,
                                                      int* __restrict__ slot_token,
                                                      float* __restrict__ slot_gate) {
    const int tk = blockIdx.x * 256 + threadIdx.x;
    if (tk >= BT) return;
#pragma unroll
    for (int ki = 0; ki < 2; ++ki) {
        const int e = eids[2 * tk + ki];
        const int idx = atomicAdd(&cur[e], 1);
        const int slot = offs[e] + idx;
        slot_token[slot] = tk;
        slot_gate[slot] = gates[2 * tk + ki];
    }
}

__global__ __launch_bounds__(256) void zero_kernel(float* __restrict__ p, int n4) {
    const int i = blockIdx.x * 256 + threadIdx.x;
    if (i < n4) ((float4*)p)[i] = make_float4(0.f, 0.f, 0.f, 0.f);
}

// ---------------- launch ------------------------------------------------------
extern "C" void kernel_launch(void* const* d_in, const int* in_sizes, int n_in,
                              void* d_out, int out_size, void* d_ws, size_t ws_size,
                              hipStream_t stream) {
    (void)in_sizes; (void)n_in; (void)out_size; (void)ws_size;
    const float* x    = (const float*)d_in[0];
    const float* Wq   = (const float*)d_in[1];
    const float* Wk   = (const float*)d_in[2];
    const float* Wv   = (const float*)d_in[3];
    const float* Wo   = (const float*)d_in[4];
    const float* bo   = (const float*)d_in[5];
    const float* ln1g = (const float*)d_in[6];
    const float* ln1b = (const float*)d_in[7];
    const float* Wr   = (const float*)d_in[8];
    const float* br   = (const float*)d_in[9];
    const float* Wn   = (const float*)d_in[10];
    const float* bn   = (const float*)d_in[11];
    const float* W1   = (const float*)d_in[12];
    const float* b1   = (const float*)d_in[13];
    const float* W2   = (const float*)d_in[14];
    const float* b2   = (const float*)d_in[15];
    const float* ln2g = (const float*)d_in[16];
    const float* ln2b = (const float*)d_in[17];
    const float* noise= (const float*)d_in[18];
    float* out = (float*)d_out;
    float* ws  = (float*)d_ws;
    int*   iws = (int*)d_ws;

    float* qb    = ws + OFF_Q;     // Q, then attn output (in-place)
    float* kb    = ws + OFF_K;
    float* vb    = ws + OFF_V;
    float* proj  = ws + OFF_V;     // V dead after attention
    float* x1    = out;            // x1 lives in d_out
    float* hbuf  = ws + OFF_Q;     // spans Q+K regions (8192 x FFC fp32)
    float* moe   = ws + OFF_V;     // proj dead after ln1
    float* gates = ws + SM_GATES;
    float* sgate = ws + SM_SGATE;
    int* eids  = iws + SM_EIDS;
    int* stok  = iws + SM_STOK;
    int* cnt   = iws + SM_CNT;
    int* offs  = iws + SM_OFFS;
    int* cur   = iws + SM_CUR;

    zero_counts_kernel<<<1, 64, 0, stream>>>(cnt);
    qkv_kernel<<<dim3(BT / 64, HH, 3), 256, 0, stream>>>(x, Wq, Wk, Wv, qb, kb, vb);
    attn_kernel<<<dim3(TT / 128, HH, BB), 256, 0, stream>>>(qb, kb, vb);
    gemm_bias_kernel<<<dim3(BT / 64, CC / 64), 256, 0, stream>>>(qb, Wo, bo, proj, CC, CC);
    ln_res_kernel<<<BT, 256, 0, stream>>>(proj, x, ln1g, ln1b, x1);
    router_kernel<<<BT, 256, 0, stream>>>(x1, Wr, br, Wn, bn, noise, gates, eids, cnt);
    offsets_kernel<<<1, 64, 0, stream>>>(cnt, offs, cur);
    scatter_kernel<<<BT / 256, 256, 0, stream>>>(eids, gates, cur, offs, stok, sgate);
    zero_kernel<<<(BT * CC / 4 + 255) / 256, 256, 0, stream>>>(moe, BT * CC / 4);
    for (int ccnk = 0; ccnk < FF / FFC; ++ccnk) {
        mm_ffn1<<<dim3(2 * BT / 128, FFC / 128, EE), 256, 0, stream>>>(
            x1, W1, b1, stok, offs, cnt, hbuf, ccnk * FFC);
        mm_ffn2<<<dim3(2 * BT / 128, CC / 128, EE), 256, 0, stream>>>(
            hbuf, W2, b2, stok, sgate, offs, cnt, moe, ccnk * FFC, ccnk == 0 ? 1 : 0);
    }
    ln_res_kernel<<<BT, 256, 0, stream>>>(moe, x1, ln2g, ln2b, out);
}